// Round 7
// baseline (430.783 us; speedup 1.0000x reference)
//
#include <hip/hip_runtime.h>
#include <hip/hip_bf16.h>
#include <stdint.h>

#define B_SZ   4096
#define TWO_B  8192
#define D_DIM  2048
#define N_TOT  15000000
#define RHO    0.8f
#define NIT    16         // iterations; each = 2 K-tiles of BK=64 (K=2048)
#define NJOB   528        // 496 off-diag (R<C) + 32 diag, 256x256 each

typedef __attribute__((ext_vector_type(8))) __bf16 bf16x8;
typedef __attribute__((ext_vector_type(4))) float f32x4;
typedef unsigned short ushort_t;

// ---------- helpers ----------
__device__ __forceinline__ ushort_t f2bf(float v) {
    __hip_bfloat16 h = __float2bfloat16(v);
    return *reinterpret_cast<ushort_t*>(&h);
}
__device__ __forceinline__ float waveReduceSum(float v) {
#pragma unroll
    for (int off = 32; off >= 1; off >>= 1) v += __shfl_down(v, off, 64);
    return v;
}
__device__ __forceinline__ void gload_lds16(const void* g, void* l) {
    __builtin_amdgcn_global_load_lds(
        (const __attribute__((address_space(1))) void*)(uintptr_t)g,
        (__attribute__((address_space(3))) void*)(uintptr_t)l,
        16, 0, 0);
}

// ---------- kernel 1: paired normalize -> bf16, + positive-pair dot ----------
__global__ __launch_bounds__(256) void knorm2(const float* __restrict__ feat,
                                              ushort_t* __restrict__ fbf,
                                              float* __restrict__ posdot) {
    int i = blockIdx.x;           // [0, B)
    int tid = threadIdx.x;
    const float4* ra = reinterpret_cast<const float4*>(feat + (size_t)i * D_DIM);
    const float4* rb = reinterpret_cast<const float4*>(feat + (size_t)(i + B_SZ) * D_DIM);
    float4 a0 = ra[tid * 2], a1 = ra[tid * 2 + 1];
    float4 b0 = rb[tid * 2], b1 = rb[tid * 2 + 1];
    float sa = a0.x*a0.x + a0.y*a0.y + a0.z*a0.z + a0.w*a0.w
             + a1.x*a1.x + a1.y*a1.y + a1.z*a1.z + a1.w*a1.w;
    float sb = b0.x*b0.x + b0.y*b0.y + b0.z*b0.z + b0.w*b0.w
             + b1.x*b1.x + b1.y*b1.y + b1.z*b1.z + b1.w*b1.w;
    float dp = a0.x*b0.x + a0.y*b0.y + a0.z*b0.z + a0.w*b0.w
             + a1.x*b1.x + a1.y*b1.y + a1.z*b1.z + a1.w*b1.w;
    sa = waveReduceSum(sa);
    sb = waveReduceSum(sb);
    dp = waveReduceSum(dp);
    __shared__ float wsum[3][4];
    if ((tid & 63) == 0) {
        int wv = tid >> 6;
        wsum[0][wv] = sa; wsum[1][wv] = sb; wsum[2][wv] = dp;
    }
    __syncthreads();
    float ta = wsum[0][0] + wsum[0][1] + wsum[0][2] + wsum[0][3];
    float tb = wsum[1][0] + wsum[1][1] + wsum[1][2] + wsum[1][3];
    float td = wsum[2][0] + wsum[2][1] + wsum[2][2] + wsum[2][3];
    float ia = 1.0f / fmaxf(sqrtf(ta), 1e-12f);
    float ib = 1.0f / fmaxf(sqrtf(tb), 1e-12f);
    if (tid == 0) posdot[i] = td * ia * ib;
    uint4 oa, ob;
    oa.x = (unsigned)f2bf(a0.x * ia) | ((unsigned)f2bf(a0.y * ia) << 16);
    oa.y = (unsigned)f2bf(a0.z * ia) | ((unsigned)f2bf(a0.w * ia) << 16);
    oa.z = (unsigned)f2bf(a1.x * ia) | ((unsigned)f2bf(a1.y * ia) << 16);
    oa.w = (unsigned)f2bf(a1.z * ia) | ((unsigned)f2bf(a1.w * ia) << 16);
    ob.x = (unsigned)f2bf(b0.x * ib) | ((unsigned)f2bf(b0.y * ib) << 16);
    ob.y = (unsigned)f2bf(b0.z * ib) | ((unsigned)f2bf(b0.w * ib) << 16);
    ob.z = (unsigned)f2bf(b1.x * ib) | ((unsigned)f2bf(b1.y * ib) << 16);
    ob.w = (unsigned)f2bf(b1.z * ib) | ((unsigned)f2bf(b1.w * ib) << 16);
    reinterpret_cast<uint4*>(fbf + (size_t)i * D_DIM)[tid] = oa;
    reinterpret_cast<uint4*>(fbf + (size_t)(i + B_SZ) * D_DIM)[tid] = ob;
}

// ---------- kernel 2: symmetric Gram, 256x256 jobs, 8-phase schedule ----------
// 512 thr / 8 waves (2M x 4N), per-wave 128x64 out, BK=64, 128 KB LDS dbuf.
// Half-tile staging pipeline; counted vmcnt(4) at phases 3,7 only.
__global__ __launch_bounds__(512, 2) void kgram(
        const ushort_t* __restrict__ fbf,
        const float* __restrict__ tau_buf, const int* __restrict__ index,
        float* __restrict__ E, float* __restrict__ F,
        const float4* __restrict__ sIn, const float4* __restrict__ uIn,
        const float4* __restrict__ tIn, float* __restrict__ out) {
    const int raw = (int)blockIdx.x;
    const int bid = (raw & 7) * (NJOB / 8) + (raw >> 3);   // XCD swizzle (528 = 8*66)
    int R, C;
    if (bid < 496) {   // off-diagonal, C-major: C(C-1)/2 <= bid < C(C+1)/2
        C = (int)((1.0f + sqrtf(1.0f + 8.0f * (float)bid)) * 0.5f);
        while (C * (C - 1) / 2 > bid) --C;
        while ((C + 1) * C / 2 <= bid) ++C;
        R = bid - C * (C - 1) / 2;
    } else {
        C = bid - 496; R = C;
    }
    const int r0 = R * 256, c0 = C * 256;

    const int tid = threadIdx.x;
    const int lane = tid & 63;
    const int w = tid >> 6;            // wave 0..7
    const int wr = w >> 2;             // 0..1 (M)
    const int wc = w & 3;              // 0..3 (N)
    const int l15 = lane & 15, lhi = lane >> 4;

    __shared__ alignas(16) ushort_t As[2][256 * 64];   // 64 KB
    __shared__ alignas(16) ushort_t Bs[2][256 * 64];   // 64 KB

    f32x4 acc[8][4] = {};
    bf16x8 af[4][2], bfr[4][2];

    // LDS read swizzle: col16' = (lhi ^ ((row>>1)&3)) + 4*ks; row bits1-2 == l15 bits1-2
    const int rc = (lhi ^ ((l15 >> 1) & 3)) * 8;
    const int aoff = (wr * 128 + l15) * 64;
    const int boff = (wc * 64 + l15) * 64;

    // staging: per gload a wave covers 8 rows x 8 chunks; source chunk pre-swizzled
    const size_t gswz = (size_t)(((lane & 7) ^ ((lane >> 4) & 3)) * 8);
    const size_t gsA = (size_t)(r0 + (lane >> 3)) * D_DIM + gswz;
    const size_t gsB = (size_t)(c0 + (lane >> 3)) * D_DIM + gswz;

#define STAGE_A(tb, h, ld, t)                                                      \
    gload_lds16(fbf + gsA + (size_t)((h) * 128 + (ld) * 64) * D_DIM + (size_t)(t) * 64, \
                &As[tb][(h) * 8192 + (ld) * 4096 + w * 512])
#define STAGE_B(tb, h, ld, t)                                                      \
    gload_lds16(fbf + gsB + (size_t)((h) * 128 + (ld) * 64) * D_DIM + (size_t)(t) * 64, \
                &Bs[tb][(h) * 8192 + (ld) * 4096 + w * 512])
#define STAGE_AH(tb, h, t) do { STAGE_A(tb, h, 0, t); STAGE_A(tb, h, 1, t); } while (0)
#define STAGE_BH(tb, h, t) do { STAGE_B(tb, h, 0, t); STAGE_B(tb, h, 1, t); } while (0)

#define LOAD_A(tb, mb) do { _Pragma("unroll") for (int mi = 0; mi < 4; ++mi) {       \
    af[mi][0] = *reinterpret_cast<const bf16x8*>(&As[tb][aoff + ((mb) + mi) * 1024 + rc]);      \
    af[mi][1] = *reinterpret_cast<const bf16x8*>(&As[tb][aoff + ((mb) + mi) * 1024 + rc + 32]); \
  } } while (0)
#define LOAD_B2(tb, nb) do { _Pragma("unroll") for (int ni = 0; ni < 2; ++ni) {      \
    bfr[(nb) + ni][0] = *reinterpret_cast<const bf16x8*>(&Bs[tb][boff + ((nb) + ni) * 1024 + rc]);      \
    bfr[(nb) + ni][1] = *reinterpret_cast<const bf16x8*>(&Bs[tb][boff + ((nb) + ni) * 1024 + rc + 32]); \
  } } while (0)
#define MFMAQ(mb, nb) do {                                                          \
    __builtin_amdgcn_s_setprio(1);                                                  \
    _Pragma("unroll") for (int mi = 0; mi < 4; ++mi)                                \
    _Pragma("unroll") for (int ni = 0; ni < 2; ++ni) {                              \
      acc[(mb)+mi][(nb)+ni] = __builtin_amdgcn_mfma_f32_16x16x32_bf16(af[mi][0], bfr[(nb)+ni][0], acc[(mb)+mi][(nb)+ni], 0, 0, 0); \
      acc[(mb)+mi][(nb)+ni] = __builtin_amdgcn_mfma_f32_16x16x32_bf16(af[mi][1], bfr[(nb)+ni][1], acc[(mb)+mi][(nb)+ni], 0, 0, 0); \
    }                                                                               \
    __builtin_amdgcn_s_setprio(0);                                                  \
  } while (0)
#define BAR()   __builtin_amdgcn_s_barrier()
#define LGKM0() do { asm volatile("s_waitcnt lgkmcnt(0)" ::: "memory"); \
                     __builtin_amdgcn_sched_barrier(0); } while (0)
#define VMC4()  do { asm volatile("s_waitcnt vmcnt(4)" ::: "memory");   \
                     __builtin_amdgcn_sched_barrier(0); } while (0)
#define VMC0()  do { asm volatile("s_waitcnt vmcnt(0)" ::: "memory");   \
                     __builtin_amdgcn_sched_barrier(0); } while (0)

    // prologue: tile0 full -> buf0; tile1 B halves -> buf1 (A halves staged in-loop)
    STAGE_AH(0, 0, 0); STAGE_AH(0, 1, 0);
    STAGE_BH(0, 0, 0); STAGE_BH(0, 1, 0);
    STAGE_BH(1, 0, 1); STAGE_BH(1, 1, 1);
    VMC4();
    BAR();

    for (int i = 0; i < NIT; ++i) {
        const int t1 = 2 * i + 1;
        const int t2 = 2 * i + 2;
        const bool stg = (i < NIT - 1);
        // phase 0: tile 2i (buf0), quad m0-3 x n0-1
        LOAD_A(0, 0); LOAD_B2(0, 0);
        STAGE_AH(1, 0, t1);
        BAR(); LGKM0();
        MFMAQ(0, 0);
        BAR();
        // phase 1: quad m0-3 x n2-3
        LOAD_B2(0, 2);
        STAGE_AH(1, 1, t1);
        BAR(); LGKM0();
        MFMAQ(0, 2);
        BAR();
        // phase 2: quad m4-7 x n0-1
        LOAD_A(0, 4);
        if (stg) STAGE_BH(0, 0, t2);
        BAR(); LGKM0();
        MFMAQ(4, 0);
        BAR();
        // phase 3: quad m4-7 x n2-3
        if (stg) { STAGE_BH(0, 1, t2); VMC4(); } else { VMC0(); }
        BAR(); LGKM0();
        MFMAQ(4, 2);
        BAR();
        // phase 4: tile 2i+1 (buf1), quad m0-3 x n0-1
        LOAD_A(1, 0); LOAD_B2(1, 0);
        if (stg) STAGE_AH(0, 0, t2);
        BAR(); LGKM0();
        MFMAQ(0, 0);
        BAR();
        // phase 5: quad m0-3 x n2-3
        LOAD_B2(1, 2);
        if (stg) STAGE_AH(0, 1, t2);
        BAR(); LGKM0();
        MFMAQ(0, 2);
        BAR();
        // phase 6: quad m4-7 x n0-1
        LOAD_A(1, 4);
        if (stg) STAGE_BH(1, 0, t2 + 1);
        BAR(); LGKM0();
        MFMAQ(4, 0);
        BAR();
        // phase 7: quad m4-7 x n2-3
        if (stg) { STAGE_BH(1, 1, t2 + 1); VMC4(); }
        BAR(); LGKM0();
        MFMAQ(4, 2);
        BAR();
    }
#undef STAGE_A
#undef STAGE_B
#undef STAGE_AH
#undef STAGE_BH
#undef LOAD_A
#undef LOAD_B2
#undef MFMAQ
#undef BAR
#undef LGKM0
#undef VMC4
#undef VMC0

    // ---- epilogue: per element col>row -> direct (row tau) + transposed (col tau) ----
#pragma unroll
    for (int m = 0; m < 8; ++m) {
#pragma unroll
        for (int r = 0; r < 4; ++r) {
            int row_g = r0 + wr * 128 + m * 16 + lhi * 4 + r;
            float it = 1.0f / tau_buf[index[row_g & (B_SZ - 1)]];
            float e = 0.f, f = 0.f;
#pragma unroll
            for (int n = 0; n < 4; ++n) {
                int col_g = c0 + wc * 64 + n * 16 + l15;
                float v = acc[m][n][r];
                if (col_g > row_g && (((row_g ^ col_g) & (B_SZ - 1)) != 0)) {
                    float ex = __expf(v * it);
                    e += ex;
                    f += ex * v;
                }
            }
#pragma unroll
            for (int off = 1; off < 16; off <<= 1) {
                e += __shfl_xor(e, off, 64);
                f += __shfl_xor(f, off, 64);
            }
            if (l15 == 0) {
                atomicAdd(&E[row_g], e);
                atomicAdd(&F[row_g], f);
            }
        }
    }
#pragma unroll
    for (int n = 0; n < 4; ++n) {
        int colT = c0 + wc * 64 + n * 16 + l15;
        float it = 1.0f / tau_buf[index[colT & (B_SZ - 1)]];
        float e = 0.f, f = 0.f;
#pragma unroll
        for (int m = 0; m < 8; ++m) {
#pragma unroll
            for (int r = 0; r < 4; ++r) {
                int row_g = r0 + wr * 128 + m * 16 + lhi * 4 + r;
                float v = acc[m][n][r];
                if (colT > row_g && (((row_g ^ colT) & (B_SZ - 1)) != 0)) {
                    float ex = __expf(v * it);
                    e += ex;
                    f += ex * v;
                }
            }
        }
        e += __shfl_xor(e, 16, 64);
        f += __shfl_xor(f, 16, 64);
        e += __shfl_xor(e, 32, 64);
        f += __shfl_xor(f, 32, 64);
        if (lhi == 0) {
            atomicAdd(&E[colT], e);
            atomicAdd(&F[colT], f);
        }
    }

    // ---- fused bulk copy s/u/tau -> out ----
    {
        typedef float4 __attribute__((aligned(4))) float4u;
        size_t i = (size_t)raw * 512 + tid;
        const size_t stride = (size_t)NJOB * 512;
        const size_t n4 = N_TOT / 4;
        for (; i < n4; i += stride) {
            *reinterpret_cast<float4u*>(out + 1 + 4 * i) = sIn[i];
            *reinterpret_cast<float4u*>(out + 1 + (size_t)N_TOT + 4 * i) = uIn[i];
            *reinterpret_cast<float4u*>(out + 1 + 2 * (size_t)N_TOT + 4 * i) = tIn[i];
        }
    }
}

// ---------- kernel 3: finalize per positive pair ----------
__global__ __launch_bounds__(64) void kfin(const float* __restrict__ E,
                                           const float* __restrict__ F,
                                           const float* __restrict__ posdot,
                                           const float* __restrict__ s,
                                           const float* __restrict__ tau_buf,
                                           const float* __restrict__ u_buf,
                                           const int* __restrict__ index,
                                           const int* __restrict__ epoch_p,
                                           float* __restrict__ out) {
    int i = blockIdx.x;     // [0, B)
    int lane = threadIdx.x; // [0, 64)
    int idx = index[i];
    bool dup = false;
    for (int j = i + 1 + lane; j < B_SZ; j += 64)
        if (index[j] == idx) dup = true;
    unsigned long long ball = __ballot(dup);

    if (lane == 0) {
        float e1 = E[i], f1 = F[i];
        float e2 = E[i + B_SZ], f2 = F[i + B_SZ];
        const float num_neg = 2.0f * B_SZ - 2.0f;
        float g1 = e1 / num_neg, g2 = e2 / num_neg;
        float s_old = s[idx];
        float tau_i = tau_buf[idx];
        float u_old = u_buf[idx];
        int ep = *epoch_p;
        float s1, s2;
        if (ep == 0) { s1 = g1; s2 = g2; }
        else { s1 = 0.2f * s_old + 0.8f * g1; s2 = 0.2f * s_old + 0.8f * g2; }
        float pos = posdot[i];
        float l1 = f1 / (s1 * num_neg) - pos;
        float l2 = f2 / (s2 * num_neg) - pos;
        atomicAdd(out, (l1 + l2) * (1.0f / B_SZ));
        float gt1 = logf(s1) + RHO - f1 / (tau_i * s1 * num_neg);
        float gt2 = logf(s2) + RHO - f2 / (tau_i * s2 * num_neg);
        float gt = 0.5f * (gt1 + gt2);
        gt = fminf(fmaxf(gt, -3.0f), 3.0f);
        float u_new = 0.1f * u_old + 0.9f * gt;
        float tau_new = fminf(fmaxf(tau_i - 0.001f * u_new, 0.05f), 1.0f);
        if (ball == 0ULL) {  // winner (numpy last-wins)
            out[1 + (size_t)idx] = 0.5f * (s1 + s2);
            out[1 + (size_t)N_TOT + idx] = u_new;
            out[1 + 2 * (size_t)N_TOT + idx] = tau_new;
        }
    }
}

extern "C" void kernel_launch(void* const* d_in, const int* in_sizes, int n_in,
                              void* d_out, int out_size, void* d_ws, size_t ws_size,
                              hipStream_t stream) {
    const float* features = (const float*)d_in[0];
    const float* s        = (const float*)d_in[1];
    const float* tau_buf  = (const float*)d_in[2];
    const float* u_buf    = (const float*)d_in[3];
    const int*   index    = (const int*)d_in[4];
    const int*   epoch    = (const int*)d_in[5];
    float* out = (float*)d_out;
    char* ws = (char*)d_ws;

    // workspace layout
    ushort_t* fbf    = (ushort_t*)(ws);                  // 33,554,432 B
    float*    E      = (float*)(ws + 33554432);          // 32 KB
    float*    F      = (float*)(ws + 33587200);          // 32 KB
    float*    posdot = (float*)(ws + 33619968);          // 16 KB

    hipMemsetAsync(d_out, 0, sizeof(float), stream);           // loss accumulator
    hipMemsetAsync(E, 0, 2 * TWO_B * sizeof(float), stream);   // E and F (contiguous)

    knorm2<<<B_SZ, 256, 0, stream>>>(features, fbf, posdot);
    kgram<<<NJOB, 512, 0, stream>>>(fbf, tau_buf, index, E, F,
                                    (const float4*)s, (const float4*)u_buf,
                                    (const float4*)tau_buf, out);
    kfin<<<B_SZ, 64, 0, stream>>>(E, F, posdot, s, tau_buf, u_buf, index, epoch, out);
}

// Round 8
// 384.779 us; speedup vs baseline: 1.1196x; 1.1196x over previous
//
#include <hip/hip_runtime.h>
#include <hip/hip_bf16.h>
#include <stdint.h>

#define B_SZ   4096
#define TWO_B  8192
#define D_DIM  2048
#define N_TOT  15000000
#define RHO    0.8f
#define NIT    16         // iterations; each covers 2 K-tiles of BK=64 (K=2048)
#define NJOB   512        // 496 off-diag (R<C) + 16 double-diag jobs (2 tiles each)

typedef __attribute__((ext_vector_type(8))) __bf16 bf16x8;
typedef __attribute__((ext_vector_type(4))) float f32x4;
typedef unsigned short ushort_t;

// ---------- helpers ----------
__device__ __forceinline__ ushort_t f2bf(float v) {
    __hip_bfloat16 h = __float2bfloat16(v);
    return *reinterpret_cast<ushort_t*>(&h);
}
__device__ __forceinline__ float waveReduceSum(float v) {
#pragma unroll
    for (int off = 32; off >= 1; off >>= 1) v += __shfl_down(v, off, 64);
    return v;
}
__device__ __forceinline__ void gload_lds16(const void* g, void* l) {
    __builtin_amdgcn_global_load_lds(
        (const __attribute__((address_space(1))) void*)(uintptr_t)g,
        (__attribute__((address_space(3))) void*)(uintptr_t)l,
        16, 0, 0);
}

// ---------- kernel 1: paired normalize -> bf16, + positive-pair dot ----------
__global__ __launch_bounds__(256) void knorm2(const float* __restrict__ feat,
                                              ushort_t* __restrict__ fbf,
                                              float* __restrict__ posdot) {
    int i = blockIdx.x;           // [0, B)
    int tid = threadIdx.x;
    const float4* ra = reinterpret_cast<const float4*>(feat + (size_t)i * D_DIM);
    const float4* rb = reinterpret_cast<const float4*>(feat + (size_t)(i + B_SZ) * D_DIM);
    float4 a0 = ra[tid * 2], a1 = ra[tid * 2 + 1];
    float4 b0 = rb[tid * 2], b1 = rb[tid * 2 + 1];
    float sa = a0.x*a0.x + a0.y*a0.y + a0.z*a0.z + a0.w*a0.w
             + a1.x*a1.x + a1.y*a1.y + a1.z*a1.z + a1.w*a1.w;
    float sb = b0.x*b0.x + b0.y*b0.y + b0.z*b0.z + b0.w*b0.w
             + b1.x*b1.x + b1.y*b1.y + b1.z*b1.z + b1.w*b1.w;
    float dp = a0.x*b0.x + a0.y*b0.y + a0.z*b0.z + a0.w*b0.w
             + a1.x*b1.x + a1.y*b1.y + a1.z*b1.z + a1.w*b1.w;
    sa = waveReduceSum(sa);
    sb = waveReduceSum(sb);
    dp = waveReduceSum(dp);
    __shared__ float wsum[3][4];
    if ((tid & 63) == 0) {
        int wv = tid >> 6;
        wsum[0][wv] = sa; wsum[1][wv] = sb; wsum[2][wv] = dp;
    }
    __syncthreads();
    float ta = wsum[0][0] + wsum[0][1] + wsum[0][2] + wsum[0][3];
    float tb = wsum[1][0] + wsum[1][1] + wsum[1][2] + wsum[1][3];
    float td = wsum[2][0] + wsum[2][1] + wsum[2][2] + wsum[2][3];
    float ia = 1.0f / fmaxf(sqrtf(ta), 1e-12f);
    float ib = 1.0f / fmaxf(sqrtf(tb), 1e-12f);
    if (tid == 0) posdot[i] = td * ia * ib;
    uint4 oa, ob;
    oa.x = (unsigned)f2bf(a0.x * ia) | ((unsigned)f2bf(a0.y * ia) << 16);
    oa.y = (unsigned)f2bf(a0.z * ia) | ((unsigned)f2bf(a0.w * ia) << 16);
    oa.z = (unsigned)f2bf(a1.x * ia) | ((unsigned)f2bf(a1.y * ia) << 16);
    oa.w = (unsigned)f2bf(a1.z * ia) | ((unsigned)f2bf(a1.w * ia) << 16);
    ob.x = (unsigned)f2bf(b0.x * ib) | ((unsigned)f2bf(b0.y * ib) << 16);
    ob.y = (unsigned)f2bf(b0.z * ib) | ((unsigned)f2bf(b0.w * ib) << 16);
    ob.z = (unsigned)f2bf(b1.x * ib) | ((unsigned)f2bf(b1.y * ib) << 16);
    ob.w = (unsigned)f2bf(b1.z * ib) | ((unsigned)f2bf(b1.w * ib) << 16);
    reinterpret_cast<uint4*>(fbf + (size_t)i * D_DIM)[tid] = oa;
    reinterpret_cast<uint4*>(fbf + (size_t)(i + B_SZ) * D_DIM)[tid] = ob;
}

// ---------- kernel 2: symmetric Gram, 256x256, 8-phase schedule ----------
// 512 thr / 8 waves (2M x 4N), per-wave 128x64 out, BK=64, 128 KB LDS dbuf.
// LDS layout per tile: [256 rows][8 chunks of 8 bf16]; chunk XOR-swizzled by (row&7).
// Staging unit = 64 rows (8 waves x 8 rows), 1 gload/wave; 2 units per phase.
// vmcnt(6) at end of phases 3 and 7 only (vmcnt(0) in last iteration's phase 3).
__global__ __launch_bounds__(512, 2) void kgram(
        const ushort_t* __restrict__ fbf,
        const float* __restrict__ tau_buf, const int* __restrict__ index,
        float* __restrict__ E, float* __restrict__ F,
        const float4* __restrict__ sIn, const float4* __restrict__ uIn,
        const float4* __restrict__ tIn, float* __restrict__ out) {
    const int raw = (int)blockIdx.x;
    const int bid = (raw & 7) * (NJOB / 8) + (raw >> 3);   // chunked XCD swizzle (512 = 8*64)
    // bid%64 in {0,1}: double-diagonal job; else off-diagonal job
    const int sub = bid & 63;
    int R0, C0, nrep;
    if (sub < 2) {
        int d = (bid >> 6) * 2 + sub;          // 0..15
        nrep = 2; R0 = 2 * d; C0 = 2 * d;      // tiles (2d,2d) and (2d+1,2d+1)
    } else {
        int oidx = (bid >> 6) * 62 + (sub - 2);  // 0..495, C-major over R<C
        int C = (int)((1.0f + sqrtf(1.0f + 8.0f * (float)oidx)) * 0.5f);
        while (C * (C - 1) / 2 > oidx) --C;
        while ((C + 1) * C / 2 <= oidx) ++C;
        nrep = 1; R0 = oidx - C * (C - 1) / 2; C0 = C;
    }

    const int tid = threadIdx.x;
    const int lane = tid & 63;
    const int w = tid >> 6;            // wave 0..7
    const int wr = w >> 2;             // 0..1 (M half, 128 rows)
    const int wc = w & 3;              // 0..3 (N quarter, 64 cols)
    const int l15 = lane & 15, lhi = lane >> 4;
    const int l3 = lane >> 3;          // row within 8-row slab
    const int sl7 = lane & 7;

    __shared__ alignas(16) ushort_t As[2][256 * 64];   // 64 KB
    __shared__ alignas(16) ushort_t Bs[2][256 * 64];   // 64 KB

    bf16x8 af[4][2], bfr[4][2];

    // read-side swizzled chunk offsets (elements): chunk = (lhi + 4*ks) ^ (l15&7)
    const int rx = l15 & 7;
    const int c0k = ((lhi) ^ rx) * 8;
    const int c1k = ((lhi + 4) ^ rx) * 8;
    const int aRow = (wr * 128 + l15) * 64;
    const int bRow = (wc * 64 + l15) * 64;
    // write-side: lane covers row (w*8 + l3), source chunk (sl7 ^ l3)
    const int schunk = (sl7 ^ l3) * 8;

#define STA(b, ld, t) gload_lds16(fbf + gArow + (size_t)(ld) * 64 * D_DIM + (size_t)(t) * 64, \
                                  &As[b][(ld) * 4096 + w * 512])
#define STB(b, ld, t) gload_lds16(fbf + gBrow + (size_t)(ld) * 64 * D_DIM + (size_t)(t) * 64, \
                                  &Bs[b][(ld) * 4096 + w * 512])
#define LOAD_A(b, mb) do { _Pragma("unroll") for (int mi = 0; mi < 4; ++mi) {                    \
    af[mi][0] = *reinterpret_cast<const bf16x8*>(&As[b][aRow + ((mb) + mi) * 1024 + c0k]);        \
    af[mi][1] = *reinterpret_cast<const bf16x8*>(&As[b][aRow + ((mb) + mi) * 1024 + c1k]);        \
  } } while (0)
#define LOAD_B2(b, nb) do { _Pragma("unroll") for (int ni = 0; ni < 2; ++ni) {                   \
    bfr[(nb) + ni][0] = *reinterpret_cast<const bf16x8*>(&Bs[b][bRow + ((nb) + ni) * 1024 + c0k]); \
    bfr[(nb) + ni][1] = *reinterpret_cast<const bf16x8*>(&Bs[b][bRow + ((nb) + ni) * 1024 + c1k]); \
  } } while (0)
#define MFMAQ(mb, nb) do {                                                                       \
    __builtin_amdgcn_s_setprio(1);                                                               \
    _Pragma("unroll") for (int mi = 0; mi < 4; ++mi)                                             \
    _Pragma("unroll") for (int ni = 0; ni < 2; ++ni) {                                           \
      acc[(mb)+mi][(nb)+ni] = __builtin_amdgcn_mfma_f32_16x16x32_bf16(af[mi][0], bfr[(nb)+ni][0], acc[(mb)+mi][(nb)+ni], 0, 0, 0); \
      acc[(mb)+mi][(nb)+ni] = __builtin_amdgcn_mfma_f32_16x16x32_bf16(af[mi][1], bfr[(nb)+ni][1], acc[(mb)+mi][(nb)+ni], 0, 0, 0); \
    }                                                                                            \
    __builtin_amdgcn_s_setprio(0);                                                               \
  } while (0)
#define BAR()   __builtin_amdgcn_s_barrier()
#define LGKM0() do { asm volatile("s_waitcnt lgkmcnt(0)" ::: "memory"); \
                     __builtin_amdgcn_sched_barrier(0); } while (0)
#define VMC(n)  do { asm volatile("s_waitcnt vmcnt(" #n ")" ::: "memory"); \
                     __builtin_amdgcn_sched_barrier(0); } while (0)

    for (int rep = 0; rep < nrep; ++rep) {
        const int r0 = (R0 + rep) * 256, c0 = (C0 + rep) * 256;
        const size_t gArow = (size_t)(r0 + w * 8 + l3) * D_DIM + schunk;
        const size_t gBrow = (size_t)(c0 + w * 8 + l3) * D_DIM + schunk;

        f32x4 acc[8][4] = {};

        // prologue: tile0 (8 units) then tile1 minus B ld2/ld3 (6 units)
        STA(0, 0, 0); STA(0, 1, 0); STA(0, 2, 0); STA(0, 3, 0);
        STB(0, 0, 0); STB(0, 1, 0); STB(0, 2, 0); STB(0, 3, 0);
        STA(1, 0, 1); STA(1, 2, 1);
        STB(1, 0, 1); STB(1, 1, 1);
        STA(1, 1, 1); STA(1, 3, 1);
        VMC(6);                    // tile0's 8 retired; tile1's 6 in flight
        BAR();

        for (int i = 0; i < NIT; ++i) {
            const int t1 = 2 * i + 1, t2 = 2 * i + 2, t3 = 2 * i + 3;
            const bool stg = (i < NIT - 1);
            // ph0: read buf0 A[m0-3],B[n0-1]; finish buf1 tile t1 (B ld2/ld3)
            LOAD_A(0, 0); LOAD_B2(0, 0);
            STB(1, 2, t1); STB(1, 3, t1);
            BAR(); LGKM0(); MFMAQ(0, 0); BAR();
            // ph1: read buf0 B[n2-3]; stage t2 A ld0,ld2 (freed by ph0)
            LOAD_B2(0, 2);
            if (stg) { STA(0, 0, t2); STA(0, 2, t2); }
            BAR(); LGKM0(); MFMAQ(0, 2); BAR();
            // ph2: read buf0 A[m4-7]; stage t2 B ld0,ld1 (freed by ph1)
            LOAD_A(0, 4);
            if (stg) { STB(0, 0, t2); STB(0, 1, t2); }
            BAR(); LGKM0(); MFMAQ(4, 0); BAR();
            // ph3: (regs ready); stage t2 A ld1,ld3 (freed by ph2); vmcnt for buf1
            if (stg) { STA(0, 1, t2); STA(0, 3, t2); }
            BAR(); LGKM0(); MFMAQ(4, 2);
            if (stg) VMC(6); else VMC(0);
            BAR();
            // ph4: read buf1 A[m0-3],B[n0-1]; stage t2 B ld2,ld3
            LOAD_A(1, 0); LOAD_B2(1, 0);
            if (stg) { STB(0, 2, t2); STB(0, 3, t2); }
            BAR(); LGKM0(); MFMAQ(0, 0); BAR();
            // ph5: read buf1 B[n2-3]; stage t3 A ld0,ld2 (freed by ph4)
            LOAD_B2(1, 2);
            if (stg) { STA(1, 0, t3); STA(1, 2, t3); }
            BAR(); LGKM0(); MFMAQ(0, 2); BAR();
            // ph6: read buf1 A[m4-7]; stage t3 B ld0,ld1 (freed by ph5)
            LOAD_A(1, 4);
            if (stg) { STB(1, 0, t3); STB(1, 1, t3); }
            BAR(); LGKM0(); MFMAQ(4, 0); BAR();
            // ph7: stage t3 A ld1,ld3 (freed by ph6); vmcnt for buf0 (next ph0)
            if (stg) { STA(1, 1, t3); STA(1, 3, t3); }
            BAR(); LGKM0(); MFMAQ(4, 2);
            VMC(6);
            BAR();
        }

        // ---- epilogue: per element col>row -> direct (row tau) + transposed (col tau) ----
#pragma unroll
        for (int m = 0; m < 8; ++m) {
#pragma unroll
            for (int r = 0; r < 4; ++r) {
                int row_g = r0 + wr * 128 + m * 16 + lhi * 4 + r;
                float it = 1.0f / tau_buf[index[row_g & (B_SZ - 1)]];
                float e = 0.f, f = 0.f;
#pragma unroll
                for (int n = 0; n < 4; ++n) {
                    int col_g = c0 + wc * 64 + n * 16 + l15;
                    float v = acc[m][n][r];
                    if (col_g > row_g && (((row_g ^ col_g) & (B_SZ - 1)) != 0)) {
                        float ex = __expf(v * it);
                        e += ex;
                        f += ex * v;
                    }
                }
#pragma unroll
                for (int off = 1; off < 16; off <<= 1) {
                    e += __shfl_xor(e, off, 64);
                    f += __shfl_xor(f, off, 64);
                }
                if (l15 == 0) {
                    atomicAdd(&E[row_g], e);
                    atomicAdd(&F[row_g], f);
                }
            }
        }
#pragma unroll
        for (int n = 0; n < 4; ++n) {
            int colT = c0 + wc * 64 + n * 16 + l15;
            float it = 1.0f / tau_buf[index[colT & (B_SZ - 1)]];
            float e = 0.f, f = 0.f;
#pragma unroll
            for (int m = 0; m < 8; ++m) {
#pragma unroll
                for (int r = 0; r < 4; ++r) {
                    int row_g = r0 + wr * 128 + m * 16 + lhi * 4 + r;
                    float v = acc[m][n][r];
                    if (colT > row_g && (((row_g ^ colT) & (B_SZ - 1)) != 0)) {
                        float ex = __expf(v * it);
                        e += ex;
                        f += ex * v;
                    }
                }
            }
            e += __shfl_xor(e, 16, 64);
            f += __shfl_xor(f, 16, 64);
            e += __shfl_xor(e, 32, 64);
            f += __shfl_xor(f, 32, 64);
            if (lhi == 0) {
                atomicAdd(&E[colT], e);
                atomicAdd(&F[colT], f);
            }
        }
    } // rep

#undef STA
#undef STB
#undef LOAD_A
#undef LOAD_B2
#undef MFMAQ
#undef BAR
#undef LGKM0
#undef VMC

    // ---- fused bulk copy s/u/tau -> out ----
    {
        typedef float4 __attribute__((aligned(4))) float4u;
        size_t i = (size_t)raw * 512 + tid;
        const size_t stride = (size_t)NJOB * 512;
        const size_t n4 = N_TOT / 4;
        for (; i < n4; i += stride) {
            *reinterpret_cast<float4u*>(out + 1 + 4 * i) = sIn[i];
            *reinterpret_cast<float4u*>(out + 1 + (size_t)N_TOT + 4 * i) = uIn[i];
            *reinterpret_cast<float4u*>(out + 1 + 2 * (size_t)N_TOT + 4 * i) = tIn[i];
        }
    }
}

// ---------- kernel 3: finalize per positive pair ----------
__global__ __launch_bounds__(64) void kfin(const float* __restrict__ E,
                                           const float* __restrict__ F,
                                           const float* __restrict__ posdot,
                                           const float* __restrict__ s,
                                           const float* __restrict__ tau_buf,
                                           const float* __restrict__ u_buf,
                                           const int* __restrict__ index,
                                           const int* __restrict__ epoch_p,
                                           float* __restrict__ out) {
    int i = blockIdx.x;     // [0, B)
    int lane = threadIdx.x; // [0, 64)
    int idx = index[i];
    bool dup = false;
    for (int j = i + 1 + lane; j < B_SZ; j += 64)
        if (index[j] == idx) dup = true;
    unsigned long long ball = __ballot(dup);

    if (lane == 0) {
        float e1 = E[i], f1 = F[i];
        float e2 = E[i + B_SZ], f2 = F[i + B_SZ];
        const float num_neg = 2.0f * B_SZ - 2.0f;
        float g1 = e1 / num_neg, g2 = e2 / num_neg;
        float s_old = s[idx];
        float tau_i = tau_buf[idx];
        float u_old = u_buf[idx];
        int ep = *epoch_p;
        float s1, s2;
        if (ep == 0) { s1 = g1; s2 = g2; }
        else { s1 = 0.2f * s_old + 0.8f * g1; s2 = 0.2f * s_old + 0.8f * g2; }
        float pos = posdot[i];
        float l1 = f1 / (s1 * num_neg) - pos;
        float l2 = f2 / (s2 * num_neg) - pos;
        atomicAdd(out, (l1 + l2) * (1.0f / B_SZ));
        float gt1 = logf(s1) + RHO - f1 / (tau_i * s1 * num_neg);
        float gt2 = logf(s2) + RHO - f2 / (tau_i * s2 * num_neg);
        float gt = 0.5f * (gt1 + gt2);
        gt = fminf(fmaxf(gt, -3.0f), 3.0f);
        float u_new = 0.1f * u_old + 0.9f * gt;
        float tau_new = fminf(fmaxf(tau_i - 0.001f * u_new, 0.05f), 1.0f);
        if (ball == 0ULL) {  // winner (numpy last-wins)
            out[1 + (size_t)idx] = 0.5f * (s1 + s2);
            out[1 + (size_t)N_TOT + idx] = u_new;
            out[1 + 2 * (size_t)N_TOT + idx] = tau_new;
        }
    }
}

extern "C" void kernel_launch(void* const* d_in, const int* in_sizes, int n_in,
                              void* d_out, int out_size, void* d_ws, size_t ws_size,
                              hipStream_t stream) {
    const float* features = (const float*)d_in[0];
    const float* s        = (const float*)d_in[1];
    const float* tau_buf  = (const float*)d_in[2];
    const float* u_buf    = (const float*)d_in[3];
    const int*   index    = (const int*)d_in[4];
    const int*   epoch    = (const int*)d_in[5];
    float* out = (float*)d_out;
    char* ws = (char*)d_ws;

    // workspace layout
    ushort_t* fbf    = (ushort_t*)(ws);                  // 33,554,432 B
    float*    E      = (float*)(ws + 33554432);          // 32 KB
    float*    F      = (float*)(ws + 33587200);          // 32 KB
    float*    posdot = (float*)(ws + 33619968);          // 16 KB

    hipMemsetAsync(d_out, 0, sizeof(float), stream);           // loss accumulator
    hipMemsetAsync(E, 0, 2 * TWO_B * sizeof(float), stream);   // E and F (contiguous)

    knorm2<<<B_SZ, 256, 0, stream>>>(features, fbf, posdot);
    kgram<<<NJOB, 512, 0, stream>>>(fbf, tau_buf, index, E, F,
                                    (const float4*)s, (const float4*)u_buf,
                                    (const float4*)tau_buf, out);
    kfin<<<B_SZ, 64, 0, stream>>>(E, F, posdot, s, tau_buf, u_buf, index, epoch, out);
}

// Round 9
// 303.389 us; speedup vs baseline: 1.4199x; 1.2683x over previous
//
#include <hip/hip_runtime.h>
#include <hip/hip_bf16.h>
#include <stdint.h>

#define B_SZ   4096
#define TWO_B  8192
#define D_DIM  2048
#define N_TOT  15000000
#define RHO    0.8f
#define NT     32         // 2048 / 64 K-tiles (fp8, BK=64)
#define NJOB   1056       // sum over C of (2C+2) jobs of 128x256
#define GT     512
#define INV_SC (1.0f/256.0f)   // undo the 16x16 input pre-scale

typedef __attribute__((ext_vector_type(4))) float f32x4;

// ---------- helpers ----------
__device__ __forceinline__ float waveReduceSum(float v) {
#pragma unroll
    for (int off = 32; off >= 1; off >>= 1) v += __shfl_down(v, off, 64);
    return v;
}
__device__ __forceinline__ void gload_lds16(const void* g, void* l) {
    __builtin_amdgcn_global_load_lds(
        (const __attribute__((address_space(1))) void*)(uintptr_t)g,
        (__attribute__((address_space(3))) void*)(uintptr_t)l,
        16, 0, 0);
}
__device__ __forceinline__ unsigned pk4(float a, float b, float c, float d) {
    int r = 0;
    r = __builtin_amdgcn_cvt_pk_fp8_f32(a, b, r, false);   // bytes 0,1
    r = __builtin_amdgcn_cvt_pk_fp8_f32(c, d, r, true);    // bytes 2,3
    return (unsigned)r;
}

// ---------- kernel 1: paired normalize -> fp8 e4m3 (x16), + positive-pair dot ----------
__global__ __launch_bounds__(256) void knorm2(const float* __restrict__ feat,
                                              unsigned char* __restrict__ f8,
                                              float* __restrict__ posdot) {
    int i = blockIdx.x;           // [0, B)
    int tid = threadIdx.x;
    const float4* ra = reinterpret_cast<const float4*>(feat + (size_t)i * D_DIM);
    const float4* rb = reinterpret_cast<const float4*>(feat + (size_t)(i + B_SZ) * D_DIM);
    float4 a0 = ra[tid * 2], a1 = ra[tid * 2 + 1];
    float4 b0 = rb[tid * 2], b1 = rb[tid * 2 + 1];
    float sa = a0.x*a0.x + a0.y*a0.y + a0.z*a0.z + a0.w*a0.w
             + a1.x*a1.x + a1.y*a1.y + a1.z*a1.z + a1.w*a1.w;
    float sb = b0.x*b0.x + b0.y*b0.y + b0.z*b0.z + b0.w*b0.w
             + b1.x*b1.x + b1.y*b1.y + b1.z*b1.z + b1.w*b1.w;
    float dp = a0.x*b0.x + a0.y*b0.y + a0.z*b0.z + a0.w*b0.w
             + a1.x*b1.x + a1.y*b1.y + a1.z*b1.z + a1.w*b1.w;
    sa = waveReduceSum(sa);
    sb = waveReduceSum(sb);
    dp = waveReduceSum(dp);
    __shared__ float wsum[3][4];
    if ((tid & 63) == 0) {
        int wv = tid >> 6;
        wsum[0][wv] = sa; wsum[1][wv] = sb; wsum[2][wv] = dp;
    }
    __syncthreads();
    float ta = wsum[0][0] + wsum[0][1] + wsum[0][2] + wsum[0][3];
    float tb = wsum[1][0] + wsum[1][1] + wsum[1][2] + wsum[1][3];
    float td = wsum[2][0] + wsum[2][1] + wsum[2][2] + wsum[2][3];
    float ia = 1.0f / fmaxf(sqrtf(ta), 1e-12f);
    float ib = 1.0f / fmaxf(sqrtf(tb), 1e-12f);
    if (tid == 0) posdot[i] = td * ia * ib;
    float xa = ia * 16.0f, xb = ib * 16.0f;   // pre-scale for e4m3 dynamic range
    uint2 oa, ob;
    oa.x = pk4(a0.x * xa, a0.y * xa, a0.z * xa, a0.w * xa);
    oa.y = pk4(a1.x * xa, a1.y * xa, a1.z * xa, a1.w * xa);
    ob.x = pk4(b0.x * xb, b0.y * xb, b0.z * xb, b0.w * xb);
    ob.y = pk4(b1.x * xb, b1.y * xb, b1.z * xb, b1.w * xb);
    reinterpret_cast<uint2*>(f8 + (size_t)i * D_DIM)[tid] = oa;
    reinterpret_cast<uint2*>(f8 + (size_t)(i + B_SZ) * D_DIM)[tid] = ob;
}

// ---------- kernel 2: symmetric Gram (fp8), 128x256 jobs, BK=64, triple-buffer,
//            counted vmcnt(3) — R4's verified schedule, dtype-swapped.
// LDS rows are 64 B (BK=64 fp8); 16B blocks XOR-swizzled by (row>>1)&3 via source.
__global__ __launch_bounds__(GT, 4) void kgram(
        const unsigned char* __restrict__ f8,
        const float* __restrict__ tau_buf, const int* __restrict__ index,
        float* __restrict__ E, float* __restrict__ F,
        const float4* __restrict__ sIn, const float4* __restrict__ uIn,
        const float4* __restrict__ tIn, float* __restrict__ out) {
    const int raw = (int)blockIdx.x;
    const int bid = (raw & 7) * (NJOB / 8) + (raw >> 3);   // chunked XCD swizzle (1056 = 8*132)
    int C = (int)((sqrtf((float)(4 * bid + 1)) - 1.0f) * 0.5f);
    while (C * C + C > bid) --C;
    while ((C + 1) * (C + 1) + (C + 1) <= bid) ++C;
    const int R = bid - C * C - C;
    const int r0 = R * 128, c0 = C * 256;

    const int tid = threadIdx.x;
    const int lane = tid & 63;
    const int w = tid >> 6;            // wave 0..7
    const int wr = w >> 2;             // 0..1 (M)
    const int wc = w & 3;              // 0..3 (N)
    const int l15 = lane & 15, lhi = lane >> 4;

    __shared__ alignas(16) unsigned char As[3][128 * 64];   // 8 KB each
    __shared__ alignas(16) unsigned char Bs[3][256 * 64];   // 16 KB each

    f32x4 acc[4][4] = {};

    // staging: wave w stages A rows w*16..+16 (1 gload), B rows w*32..+32 (2 gloads).
    // lane covers (row rr = lane>>2, 16B-block jl = lane&3); source block = jl ^ ((rr>>1)&3)
    const int rr = lane >> 2;
    const int sj = (lane & 3) ^ ((rr >> 1) & 3);
    const size_t gA  = (size_t)(r0 + w * 16 + rr) * D_DIM + sj * 16;
    const size_t gB0 = (size_t)(c0 + w * 32 + rr) * D_DIM + sj * 16;
    const size_t gB1 = gB0 + 16 * D_DIM;
    const int lA = w * 1024, lB0 = w * 2048, lB1 = w * 2048 + 1024;

#define STAGE(buf, t)                                              \
    do {                                                           \
        size_t k_ = (size_t)(t) * 64u;                             \
        gload_lds16(f8 + gA + k_,  &As[buf][lA]);                  \
        gload_lds16(f8 + gB0 + k_, &Bs[buf][lB0]);                 \
        gload_lds16(f8 + gB1 + k_, &Bs[buf][lB1]);                 \
    } while (0)

    STAGE(0, 0);
    STAGE(1, 1);
    asm volatile("s_waitcnt vmcnt(3)" ::: "memory");
    __builtin_amdgcn_sched_barrier(0);
    __builtin_amdgcn_s_barrier();

    // read-side: slot s = lhi + 4*ks (8B units); byte = ((s>>1)^kx)*16 + (s&1)*8
    const int kx = (l15 >> 1) & 3;
    const int pk0 = (((lhi >> 1) ^ kx) * 16) + (lhi & 1) * 8;        // ks=0
    const int pk1 = ((((lhi >> 1) + 2) ^ kx) * 16) + (lhi & 1) * 8;  // ks=1

    int bufc = 0;
    for (int t = 0; t < NT; ++t) {
        if (t + 2 < NT) {
            int bw = (bufc >= 1) ? bufc - 1 : 2;     // (bufc+2)%3
            STAGE(bw, t + 2);
        }
        const unsigned char* __restrict__ A_l = &As[bufc][0];
        const unsigned char* __restrict__ B_l = &Bs[bufc][0];
        long af[4][2], bfr[4][2];
#pragma unroll
        for (int m = 0; m < 4; ++m) {
            int rowb = (wr * 64 + m * 16 + l15) * 64;
            af[m][0] = *reinterpret_cast<const long*>(&A_l[rowb + pk0]);
            af[m][1] = *reinterpret_cast<const long*>(&A_l[rowb + pk1]);
        }
#pragma unroll
        for (int n = 0; n < 4; ++n) {
            int rowb = (wc * 64 + n * 16 + l15) * 64;
            bfr[n][0] = *reinterpret_cast<const long*>(&B_l[rowb + pk0]);
            bfr[n][1] = *reinterpret_cast<const long*>(&B_l[rowb + pk1]);
        }
        __builtin_amdgcn_s_setprio(1);
#pragma unroll
        for (int m = 0; m < 4; ++m)
#pragma unroll
            for (int n = 0; n < 4; ++n) {
                acc[m][n] = __builtin_amdgcn_mfma_f32_16x16x32_fp8_fp8(af[m][0], bfr[n][0], acc[m][n], 0, 0, 0);
                acc[m][n] = __builtin_amdgcn_mfma_f32_16x16x32_fp8_fp8(af[m][1], bfr[n][1], acc[m][n], 0, 0, 0);
            }
        __builtin_amdgcn_s_setprio(0);
        if (t < NT - 2) {
            asm volatile("s_waitcnt vmcnt(3)" ::: "memory");   // tile t+1 landed; t+2 flies
        } else if (t == NT - 2) {
            asm volatile("s_waitcnt vmcnt(0)" ::: "memory");
        }
        __builtin_amdgcn_sched_barrier(0);
        if (t < NT - 1) __builtin_amdgcn_s_barrier();
        bufc = (bufc == 2) ? 0 : bufc + 1;
    }
#undef STAGE

    // ---- epilogue: per element col>row -> direct (row tau) + transposed (col tau) ----
#pragma unroll
    for (int m = 0; m < 4; ++m) {
#pragma unroll
        for (int r = 0; r < 4; ++r) {
            int row_g = r0 + wr * 64 + m * 16 + lhi * 4 + r;
            float it = 1.0f / tau_buf[index[row_g & (B_SZ - 1)]];
            float e = 0.f, f = 0.f;
#pragma unroll
            for (int n = 0; n < 4; ++n) {
                int col_g = c0 + wc * 64 + n * 16 + l15;
                float v = acc[m][n][r] * INV_SC;
                if (col_g > row_g && (((row_g ^ col_g) & (B_SZ - 1)) != 0)) {
                    float ex = __expf(v * it);
                    e += ex;
                    f += ex * v;
                }
            }
#pragma unroll
            for (int off = 1; off < 16; off <<= 1) {
                e += __shfl_xor(e, off, 64);
                f += __shfl_xor(f, off, 64);
            }
            if (l15 == 0) {
                atomicAdd(&E[row_g], e);
                atomicAdd(&F[row_g], f);
            }
        }
    }
#pragma unroll
    for (int n = 0; n < 4; ++n) {
        int colT = c0 + wc * 64 + n * 16 + l15;
        float it = 1.0f / tau_buf[index[colT & (B_SZ - 1)]];
        float e = 0.f, f = 0.f;
#pragma unroll
        for (int m = 0; m < 4; ++m) {
#pragma unroll
            for (int r = 0; r < 4; ++r) {
                int row_g = r0 + wr * 64 + m * 16 + lhi * 4 + r;
                float v = acc[m][n][r] * INV_SC;
                if (colT > row_g && (((row_g ^ colT) & (B_SZ - 1)) != 0)) {
                    float ex = __expf(v * it);
                    e += ex;
                    f += ex * v;
                }
            }
        }
        e += __shfl_xor(e, 16, 64);
        f += __shfl_xor(f, 16, 64);
        e += __shfl_xor(e, 32, 64);
        f += __shfl_xor(f, 32, 64);
        if (lhi == 0) {
            atomicAdd(&E[colT], e);
            atomicAdd(&F[colT], f);
        }
    }

    // ---- fused bulk copy s/u/tau -> out ----
    {
        typedef float4 __attribute__((aligned(4))) float4u;
        size_t i = (size_t)raw * GT + tid;
        const size_t stride = (size_t)NJOB * GT;
        const size_t n4 = N_TOT / 4;
        for (; i < n4; i += stride) {
            *reinterpret_cast<float4u*>(out + 1 + 4 * i) = sIn[i];
            *reinterpret_cast<float4u*>(out + 1 + (size_t)N_TOT + 4 * i) = uIn[i];
            *reinterpret_cast<float4u*>(out + 1 + 2 * (size_t)N_TOT + 4 * i) = tIn[i];
        }
    }
}

// ---------- kernel 3: finalize per positive pair ----------
__global__ __launch_bounds__(64) void kfin(const float* __restrict__ E,
                                           const float* __restrict__ F,
                                           const float* __restrict__ posdot,
                                           const float* __restrict__ s,
                                           const float* __restrict__ tau_buf,
                                           const float* __restrict__ u_buf,
                                           const int* __restrict__ index,
                                           const int* __restrict__ epoch_p,
                                           float* __restrict__ out) {
    int i = blockIdx.x;     // [0, B)
    int lane = threadIdx.x; // [0, 64)
    int idx = index[i];
    bool dup = false;
    for (int j = i + 1 + lane; j < B_SZ; j += 64)
        if (index[j] == idx) dup = true;
    unsigned long long ball = __ballot(dup);

    if (lane == 0) {
        float e1 = E[i], f1 = F[i];
        float e2 = E[i + B_SZ], f2 = F[i + B_SZ];
        const float num_neg = 2.0f * B_SZ - 2.0f;
        float g1 = e1 / num_neg, g2 = e2 / num_neg;
        float s_old = s[idx];
        float tau_i = tau_buf[idx];
        float u_old = u_buf[idx];
        int ep = *epoch_p;
        float s1, s2;
        if (ep == 0) { s1 = g1; s2 = g2; }
        else { s1 = 0.2f * s_old + 0.8f * g1; s2 = 0.2f * s_old + 0.8f * g2; }
        float pos = posdot[i];
        float l1 = f1 / (s1 * num_neg) - pos;
        float l2 = f2 / (s2 * num_neg) - pos;
        atomicAdd(out, (l1 + l2) * (1.0f / B_SZ));
        float gt1 = logf(s1) + RHO - f1 / (tau_i * s1 * num_neg);
        float gt2 = logf(s2) + RHO - f2 / (tau_i * s2 * num_neg);
        float gt = 0.5f * (gt1 + gt2);
        gt = fminf(fmaxf(gt, -3.0f), 3.0f);
        float u_new = 0.1f * u_old + 0.9f * gt;
        float tau_new = fminf(fmaxf(tau_i - 0.001f * u_new, 0.05f), 1.0f);
        if (ball == 0ULL) {  // winner (numpy last-wins)
            out[1 + (size_t)idx] = 0.5f * (s1 + s2);
            out[1 + (size_t)N_TOT + idx] = u_new;
            out[1 + 2 * (size_t)N_TOT + idx] = tau_new;
        }
    }
}

extern "C" void kernel_launch(void* const* d_in, const int* in_sizes, int n_in,
                              void* d_out, int out_size, void* d_ws, size_t ws_size,
                              hipStream_t stream) {
    const float* features = (const float*)d_in[0];
    const float* s        = (const float*)d_in[1];
    const float* tau_buf  = (const float*)d_in[2];
    const float* u_buf    = (const float*)d_in[3];
    const int*   index    = (const int*)d_in[4];
    const int*   epoch    = (const int*)d_in[5];
    float* out = (float*)d_out;
    char* ws = (char*)d_ws;

    // workspace layout
    unsigned char* f8     = (unsigned char*)(ws);        // 8192*2048 = 16,777,216 B
    float*         E      = (float*)(ws + 16777216);     // 32 KB
    float*         F      = (float*)(ws + 16809984);     // 32 KB
    float*         posdot = (float*)(ws + 16842752);     // 16 KB

    hipMemsetAsync(d_out, 0, sizeof(float), stream);           // loss accumulator
    hipMemsetAsync(E, 0, 2 * TWO_B * sizeof(float), stream);   // E and F (contiguous)

    knorm2<<<B_SZ, 256, 0, stream>>>(features, f8, posdot);
    kgram<<<NJOB, GT, 0, stream>>>(f8, tau_buf, index, E, F,
                                   (const float4*)s, (const float4*)u_buf,
                                   (const float4*)tau_buf, out);
    kfin<<<B_SZ, 64, 0, stream>>>(E, F, posdot, s, tau_buf, u_buf, index, epoch, out);
}

// Round 10
// 299.440 us; speedup vs baseline: 1.4386x; 1.0132x over previous
//
#include <hip/hip_runtime.h>
#include <hip/hip_bf16.h>
#include <stdint.h>

#define B_SZ   4096
#define TWO_B  8192
#define D_DIM  2048
#define N_TOT  15000000
#define RHO    0.8f
#define NT     32         // 2048 / 64 K-tiles (fp8, BK=64)
#define NJOB   1024       // main jobs: cells 0..1023 (C-major over upper-tri 128x256 cells)
#define NSLV   256        // 32 remaining cells (C=31, R=32..63) x 8 slivers of 16x256
#define GT     512
#define INV_SC (1.0f/256.0f)   // undo the 16x16 input pre-scale

typedef __attribute__((ext_vector_type(4))) float f32x4;

// ---------- helpers ----------
__device__ __forceinline__ float waveReduceSum(float v) {
#pragma unroll
    for (int off = 32; off >= 1; off >>= 1) v += __shfl_down(v, off, 64);
    return v;
}
__device__ __forceinline__ void gload_lds16(const void* g, void* l) {
    __builtin_amdgcn_global_load_lds(
        (const __attribute__((address_space(1))) void*)(uintptr_t)g,
        (__attribute__((address_space(3))) void*)(uintptr_t)l,
        16, 0, 0);
}
__device__ __forceinline__ unsigned pk4(float a, float b, float c, float d) {
    int r = 0;
    r = __builtin_amdgcn_cvt_pk_fp8_f32(a, b, r, false);   // bytes 0,1
    r = __builtin_amdgcn_cvt_pk_fp8_f32(c, d, r, true);    // bytes 2,3
    return (unsigned)r;
}

// ---------- kernel 1: paired normalize -> fp8 e4m3 (x16), + positive-pair dot ----------
__global__ __launch_bounds__(256) void knorm2(const float* __restrict__ feat,
                                              unsigned char* __restrict__ f8,
                                              float* __restrict__ posdot) {
    int i = blockIdx.x;           // [0, B)
    int tid = threadIdx.x;
    const float4* ra = reinterpret_cast<const float4*>(feat + (size_t)i * D_DIM);
    const float4* rb = reinterpret_cast<const float4*>(feat + (size_t)(i + B_SZ) * D_DIM);
    float4 a0 = ra[tid * 2], a1 = ra[tid * 2 + 1];
    float4 b0 = rb[tid * 2], b1 = rb[tid * 2 + 1];
    float sa = a0.x*a0.x + a0.y*a0.y + a0.z*a0.z + a0.w*a0.w
             + a1.x*a1.x + a1.y*a1.y + a1.z*a1.z + a1.w*a1.w;
    float sb = b0.x*b0.x + b0.y*b0.y + b0.z*b0.z + b0.w*b0.w
             + b1.x*b1.x + b1.y*b1.y + b1.z*b1.z + b1.w*b1.w;
    float dp = a0.x*b0.x + a0.y*b0.y + a0.z*b0.z + a0.w*b0.w
             + a1.x*b1.x + a1.y*b1.y + a1.z*b1.z + a1.w*b1.w;
    sa = waveReduceSum(sa);
    sb = waveReduceSum(sb);
    dp = waveReduceSum(dp);
    __shared__ float wsum[3][4];
    if ((tid & 63) == 0) {
        int wv = tid >> 6;
        wsum[0][wv] = sa; wsum[1][wv] = sb; wsum[2][wv] = dp;
    }
    __syncthreads();
    float ta = wsum[0][0] + wsum[0][1] + wsum[0][2] + wsum[0][3];
    float tb = wsum[1][0] + wsum[1][1] + wsum[1][2] + wsum[1][3];
    float td = wsum[2][0] + wsum[2][1] + wsum[2][2] + wsum[2][3];
    float ia = 1.0f / fmaxf(sqrtf(ta), 1e-12f);
    float ib = 1.0f / fmaxf(sqrtf(tb), 1e-12f);
    if (tid == 0) posdot[i] = td * ia * ib;
    float xa = ia * 16.0f, xb = ib * 16.0f;   // pre-scale for e4m3 dynamic range
    uint2 oa, ob;
    oa.x = pk4(a0.x * xa, a0.y * xa, a0.z * xa, a0.w * xa);
    oa.y = pk4(a1.x * xa, a1.y * xa, a1.z * xa, a1.w * xa);
    ob.x = pk4(b0.x * xb, b0.y * xb, b0.z * xb, b0.w * xb);
    ob.y = pk4(b1.x * xb, b1.y * xb, b1.z * xb, b1.w * xb);
    reinterpret_cast<uint2*>(f8 + (size_t)i * D_DIM)[tid] = oa;
    reinterpret_cast<uint2*>(f8 + (size_t)(i + B_SZ) * D_DIM)[tid] = ob;
}

// ---------- kernel 2: symmetric Gram (fp8), 128x256 jobs, BK=64, triple-buffer,
//            counted vmcnt(3). Cells 0..1023 only (2 exact residency rounds).
__global__ __launch_bounds__(GT, 4) void kgram(
        const unsigned char* __restrict__ f8,
        const float* __restrict__ tau_buf, const int* __restrict__ index,
        float* __restrict__ E, float* __restrict__ F,
        const float4* __restrict__ sIn, const float4* __restrict__ uIn,
        const float4* __restrict__ tIn, float* __restrict__ out) {
    const int raw = (int)blockIdx.x;
    const int bid = (raw & 7) * (NJOB / 8) + (raw >> 3);   // chunked XCD swizzle (1024 = 8*128)
    int C = (int)((sqrtf((float)(4 * bid + 1)) - 1.0f) * 0.5f);
    while (C * C + C > bid) --C;
    while ((C + 1) * (C + 1) + (C + 1) <= bid) ++C;
    const int R = bid - C * C - C;
    const int r0 = R * 128, c0 = C * 256;

    const int tid = threadIdx.x;
    const int lane = tid & 63;
    const int w = tid >> 6;            // wave 0..7
    const int wr = w >> 2;             // 0..1 (M)
    const int wc = w & 3;              // 0..3 (N)
    const int l15 = lane & 15, lhi = lane >> 4;

    __shared__ alignas(16) unsigned char As[3][128 * 64];   // 8 KB each
    __shared__ alignas(16) unsigned char Bs[3][256 * 64];   // 16 KB each

    f32x4 acc[4][4] = {};

    // staging: wave w stages A rows w*16..+16 (1 gload), B rows w*32..+32 (2 gloads).
    const int rr = lane >> 2;
    const int sj = (lane & 3) ^ ((rr >> 1) & 3);
    const size_t gA  = (size_t)(r0 + w * 16 + rr) * D_DIM + sj * 16;
    const size_t gB0 = (size_t)(c0 + w * 32 + rr) * D_DIM + sj * 16;
    const size_t gB1 = gB0 + 16 * D_DIM;
    const int lA = w * 1024, lB0 = w * 2048, lB1 = w * 2048 + 1024;

#define STAGE(buf, t)                                              \
    do {                                                           \
        size_t k_ = (size_t)(t) * 64u;                             \
        gload_lds16(f8 + gA + k_,  &As[buf][lA]);                  \
        gload_lds16(f8 + gB0 + k_, &Bs[buf][lB0]);                 \
        gload_lds16(f8 + gB1 + k_, &Bs[buf][lB1]);                 \
    } while (0)

    STAGE(0, 0);
    STAGE(1, 1);
    asm volatile("s_waitcnt vmcnt(3)" ::: "memory");
    __builtin_amdgcn_sched_barrier(0);
    __builtin_amdgcn_s_barrier();

    // read-side: slot s = lhi + 4*ks (8B units); byte = ((s>>1)^kx)*16 + (s&1)*8
    const int kx = (l15 >> 1) & 3;
    const int pk0 = (((lhi >> 1) ^ kx) * 16) + (lhi & 1) * 8;        // ks=0
    const int pk1 = ((((lhi >> 1) + 2) ^ kx) * 16) + (lhi & 1) * 8;  // ks=1

    int bufc = 0;
    for (int t = 0; t < NT; ++t) {
        if (t + 2 < NT) {
            int bw = (bufc >= 1) ? bufc - 1 : 2;     // (bufc+2)%3
            STAGE(bw, t + 2);
        }
        const unsigned char* __restrict__ A_l = &As[bufc][0];
        const unsigned char* __restrict__ B_l = &Bs[bufc][0];
        long af[4][2], bfr[4][2];
#pragma unroll
        for (int m = 0; m < 4; ++m) {
            int rowb = (wr * 64 + m * 16 + l15) * 64;
            af[m][0] = *reinterpret_cast<const long*>(&A_l[rowb + pk0]);
            af[m][1] = *reinterpret_cast<const long*>(&A_l[rowb + pk1]);
        }
#pragma unroll
        for (int n = 0; n < 4; ++n) {
            int rowb = (wc * 64 + n * 16 + l15) * 64;
            bfr[n][0] = *reinterpret_cast<const long*>(&B_l[rowb + pk0]);
            bfr[n][1] = *reinterpret_cast<const long*>(&B_l[rowb + pk1]);
        }
        __builtin_amdgcn_s_setprio(1);
#pragma unroll
        for (int m = 0; m < 4; ++m)
#pragma unroll
            for (int n = 0; n < 4; ++n) {
                acc[m][n] = __builtin_amdgcn_mfma_f32_16x16x32_fp8_fp8(af[m][0], bfr[n][0], acc[m][n], 0, 0, 0);
                acc[m][n] = __builtin_amdgcn_mfma_f32_16x16x32_fp8_fp8(af[m][1], bfr[n][1], acc[m][n], 0, 0, 0);
            }
        __builtin_amdgcn_s_setprio(0);
        if (t < NT - 2) {
            asm volatile("s_waitcnt vmcnt(3)" ::: "memory");   // tile t+1 landed; t+2 flies
        } else if (t == NT - 2) {
            asm volatile("s_waitcnt vmcnt(0)" ::: "memory");
        }
        __builtin_amdgcn_sched_barrier(0);
        if (t < NT - 1) __builtin_amdgcn_s_barrier();
        bufc = (bufc == 2) ? 0 : bufc + 1;
    }
#undef STAGE

    // ---- epilogue: per element col>row -> direct (row tau) + transposed (col tau) ----
#pragma unroll
    for (int m = 0; m < 4; ++m) {
#pragma unroll
        for (int r = 0; r < 4; ++r) {
            int row_g = r0 + wr * 64 + m * 16 + lhi * 4 + r;
            float it = 1.0f / tau_buf[index[row_g & (B_SZ - 1)]];
            float e = 0.f, f = 0.f;
#pragma unroll
            for (int n = 0; n < 4; ++n) {
                int col_g = c0 + wc * 64 + n * 16 + l15;
                float v = acc[m][n][r] * INV_SC;
                if (col_g > row_g && (((row_g ^ col_g) & (B_SZ - 1)) != 0)) {
                    float ex = __expf(v * it);
                    e += ex;
                    f += ex * v;
                }
            }
#pragma unroll
            for (int off = 1; off < 16; off <<= 1) {
                e += __shfl_xor(e, off, 64);
                f += __shfl_xor(f, off, 64);
            }
            if (l15 == 0) {
                atomicAdd(&E[row_g], e);
                atomicAdd(&F[row_g], f);
            }
        }
    }
#pragma unroll
    for (int n = 0; n < 4; ++n) {
        int colT = c0 + wc * 64 + n * 16 + l15;
        float it = 1.0f / tau_buf[index[colT & (B_SZ - 1)]];
        float e = 0.f, f = 0.f;
#pragma unroll
        for (int m = 0; m < 4; ++m) {
#pragma unroll
            for (int r = 0; r < 4; ++r) {
                int row_g = r0 + wr * 64 + m * 16 + lhi * 4 + r;
                float v = acc[m][n][r] * INV_SC;
                if (colT > row_g && (((row_g ^ colT) & (B_SZ - 1)) != 0)) {
                    float ex = __expf(v * it);
                    e += ex;
                    f += ex * v;
                }
            }
        }
        e += __shfl_xor(e, 16, 64);
        f += __shfl_xor(f, 16, 64);
        e += __shfl_xor(e, 32, 64);
        f += __shfl_xor(f, 32, 64);
        if (lhi == 0) {
            atomicAdd(&E[colT], e);
            atomicAdd(&F[colT], f);
        }
    }

    // ---- fused bulk copy s/u/tau -> out ----
    {
        typedef float4 __attribute__((aligned(4))) float4u;
        size_t i = (size_t)raw * GT + tid;
        const size_t stride = (size_t)NJOB * GT;
        const size_t n4 = N_TOT / 4;
        for (; i < n4; i += stride) {
            *reinterpret_cast<float4u*>(out + 1 + 4 * i) = sIn[i];
            *reinterpret_cast<float4u*>(out + 1 + (size_t)N_TOT + 4 * i) = uIn[i];
            *reinterpret_cast<float4u*>(out + 1 + 2 * (size_t)N_TOT + 4 * i) = tIn[i];
        }
    }
}

// ---------- kernel 2b: sliver jobs — cells (C=31, R=32..63) split into 16x256 ----------
// 256 blocks, all resident at once; same BK=64 / 3-buffer / vmcnt(3) cadence.
// 8 waves: wave w covers cols w*32..w*32+31 (2 n-frags); all waves share the 16-row A slab.
__global__ __launch_bounds__(GT, 4) void ksliver(
        const unsigned char* __restrict__ f8,
        const float* __restrict__ tau_buf, const int* __restrict__ index,
        float* __restrict__ E, float* __restrict__ F) {
    const int sb = (int)blockIdx.x;          // 0..255
    const int R = 32 + (sb >> 3);            // 32..63
    const int sv = sb & 7;                   // sliver within cell
    const int r0 = R * 128 + sv * 16;
    const int c0 = 31 * 256;

    const int tid = threadIdx.x;
    const int lane = tid & 63;
    const int w = tid >> 6;                  // wave 0..7
    const int l15 = lane & 15, lhi = lane >> 4;

    __shared__ alignas(16) unsigned char As[3][16 * 64];    // 1 KB each
    __shared__ alignas(16) unsigned char Bs[3][256 * 64];   // 16 KB each

    f32x4 acc[2] = {};

    const int rr = lane >> 2;
    const int sj = (lane & 3) ^ ((rr >> 1) & 3);
    const size_t gA  = (size_t)(r0 + rr) * D_DIM + sj * 16;          // same for all waves
    const size_t gB0 = (size_t)(c0 + w * 32 + rr) * D_DIM + sj * 16;
    const size_t gB1 = gB0 + 16 * D_DIM;
    const int lB0 = w * 2048, lB1 = w * 2048 + 1024;

#define STAGE(buf, t)                                              \
    do {                                                           \
        size_t k_ = (size_t)(t) * 64u;                             \
        gload_lds16(f8 + gA + k_,  &As[buf][0]);                   \
        gload_lds16(f8 + gB0 + k_, &Bs[buf][lB0]);                 \
        gload_lds16(f8 + gB1 + k_, &Bs[buf][lB1]);                 \
    } while (0)

    STAGE(0, 0);
    STAGE(1, 1);
    asm volatile("s_waitcnt vmcnt(3)" ::: "memory");
    __builtin_amdgcn_sched_barrier(0);
    __builtin_amdgcn_s_barrier();

    const int kx = (l15 >> 1) & 3;
    const int pk0 = (((lhi >> 1) ^ kx) * 16) + (lhi & 1) * 8;
    const int pk1 = ((((lhi >> 1) + 2) ^ kx) * 16) + (lhi & 1) * 8;

    int bufc = 0;
    for (int t = 0; t < NT; ++t) {
        if (t + 2 < NT) {
            int bw = (bufc >= 1) ? bufc - 1 : 2;
            STAGE(bw, t + 2);
        }
        const unsigned char* __restrict__ A_l = &As[bufc][0];
        const unsigned char* __restrict__ B_l = &Bs[bufc][0];
        long af0, af1, bfr[2][2];
        {
            int rowb = l15 * 64;
            af0 = *reinterpret_cast<const long*>(&A_l[rowb + pk0]);
            af1 = *reinterpret_cast<const long*>(&A_l[rowb + pk1]);
        }
#pragma unroll
        for (int n = 0; n < 2; ++n) {
            int rowb = (w * 32 + n * 16 + l15) * 64;
            bfr[n][0] = *reinterpret_cast<const long*>(&B_l[rowb + pk0]);
            bfr[n][1] = *reinterpret_cast<const long*>(&B_l[rowb + pk1]);
        }
        __builtin_amdgcn_s_setprio(1);
#pragma unroll
        for (int n = 0; n < 2; ++n) {
            acc[n] = __builtin_amdgcn_mfma_f32_16x16x32_fp8_fp8(af0, bfr[n][0], acc[n], 0, 0, 0);
            acc[n] = __builtin_amdgcn_mfma_f32_16x16x32_fp8_fp8(af1, bfr[n][1], acc[n], 0, 0, 0);
        }
        __builtin_amdgcn_s_setprio(0);
        if (t < NT - 2) {
            asm volatile("s_waitcnt vmcnt(3)" ::: "memory");
        } else if (t == NT - 2) {
            asm volatile("s_waitcnt vmcnt(0)" ::: "memory");
        }
        __builtin_amdgcn_sched_barrier(0);
        if (t < NT - 1) __builtin_amdgcn_s_barrier();
        bufc = (bufc == 2) ? 0 : bufc + 1;
    }
#undef STAGE

    // ---- epilogue ----
#pragma unroll
    for (int r = 0; r < 4; ++r) {
        int row_g = r0 + lhi * 4 + r;
        float it = 1.0f / tau_buf[index[row_g & (B_SZ - 1)]];
        float e = 0.f, f = 0.f;
#pragma unroll
        for (int n = 0; n < 2; ++n) {
            int col_g = c0 + w * 32 + n * 16 + l15;
            float v = acc[n][r] * INV_SC;
            if (col_g > row_g && (((row_g ^ col_g) & (B_SZ - 1)) != 0)) {
                float ex = __expf(v * it);
                e += ex;
                f += ex * v;
            }
        }
#pragma unroll
        for (int off = 1; off < 16; off <<= 1) {
            e += __shfl_xor(e, off, 64);
            f += __shfl_xor(f, off, 64);
        }
        if (l15 == 0) {
            atomicAdd(&E[row_g], e);
            atomicAdd(&F[row_g], f);
        }
    }
#pragma unroll
    for (int n = 0; n < 2; ++n) {
        int colT = c0 + w * 32 + n * 16 + l15;
        float it = 1.0f / tau_buf[index[colT & (B_SZ - 1)]];
        float e = 0.f, f = 0.f;
#pragma unroll
        for (int r = 0; r < 4; ++r) {
            int row_g = r0 + lhi * 4 + r;
            float v = acc[n][r] * INV_SC;
            if (colT > row_g && (((row_g ^ colT) & (B_SZ - 1)) != 0)) {
                float ex = __expf(v * it);
                e += ex;
                f += ex * v;
            }
        }
        e += __shfl_xor(e, 16, 64);
        f += __shfl_xor(f, 16, 64);
        e += __shfl_xor(e, 32, 64);
        f += __shfl_xor(f, 32, 64);
        if (lhi == 0) {
            atomicAdd(&E[colT], e);
            atomicAdd(&F[colT], f);
        }
    }
}

// ---------- kernel 3: finalize per positive pair ----------
__global__ __launch_bounds__(64) void kfin(const float* __restrict__ E,
                                           const float* __restrict__ F,
                                           const float* __restrict__ posdot,
                                           const float* __restrict__ s,
                                           const float* __restrict__ tau_buf,
                                           const float* __restrict__ u_buf,
                                           const int* __restrict__ index,
                                           const int* __restrict__ epoch_p,
                                           float* __restrict__ out) {
    int i = blockIdx.x;     // [0, B)
    int lane = threadIdx.x; // [0, 64)
    int idx = index[i];
    bool dup = false;
    for (int j = i + 1 + lane; j < B_SZ; j += 64)
        if (index[j] == idx) dup = true;
    unsigned long long ball = __ballot(dup);

    if (lane == 0) {
        float e1 = E[i], f1 = F[i];
        float e2 = E[i + B_SZ], f2 = F[i + B_SZ];
        const float num_neg = 2.0f * B_SZ - 2.0f;
        float g1 = e1 / num_neg, g2 = e2 / num_neg;
        float s_old = s[idx];
        float tau_i = tau_buf[idx];
        float u_old = u_buf[idx];
        int ep = *epoch_p;
        float s1, s2;
        if (ep == 0) { s1 = g1; s2 = g2; }
        else { s1 = 0.2f * s_old + 0.8f * g1; s2 = 0.2f * s_old + 0.8f * g2; }
        float pos = posdot[i];
        float l1 = f1 / (s1 * num_neg) - pos;
        float l2 = f2 / (s2 * num_neg) - pos;
        atomicAdd(out, (l1 + l2) * (1.0f / B_SZ));
        float gt1 = logf(s1) + RHO - f1 / (tau_i * s1 * num_neg);
        float gt2 = logf(s2) + RHO - f2 / (tau_i * s2 * num_neg);
        float gt = 0.5f * (gt1 + gt2);
        gt = fminf(fmaxf(gt, -3.0f), 3.0f);
        float u_new = 0.1f * u_old + 0.9f * gt;
        float tau_new = fminf(fmaxf(tau_i - 0.001f * u_new, 0.05f), 1.0f);
        if (ball == 0ULL) {  // winner (numpy last-wins)
            out[1 + (size_t)idx] = 0.5f * (s1 + s2);
            out[1 + (size_t)N_TOT + idx] = u_new;
            out[1 + 2 * (size_t)N_TOT + idx] = tau_new;
        }
    }
}

extern "C" void kernel_launch(void* const* d_in, const int* in_sizes, int n_in,
                              void* d_out, int out_size, void* d_ws, size_t ws_size,
                              hipStream_t stream) {
    const float* features = (const float*)d_in[0];
    const float* s        = (const float*)d_in[1];
    const float* tau_buf  = (const float*)d_in[2];
    const float* u_buf    = (const float*)d_in[3];
    const int*   index    = (const int*)d_in[4];
    const int*   epoch    = (const int*)d_in[5];
    float* out = (float*)d_out;
    char* ws = (char*)d_ws;

    // workspace layout
    unsigned char* f8     = (unsigned char*)(ws);        // 8192*2048 = 16,777,216 B
    float*         E      = (float*)(ws + 16777216);     // 32 KB
    float*         F      = (float*)(ws + 16809984);     // 32 KB
    float*         posdot = (float*)(ws + 16842752);     // 16 KB

    hipMemsetAsync(d_out, 0, sizeof(float), stream);           // loss accumulator
    hipMemsetAsync(E, 0, 2 * TWO_B * sizeof(float), stream);   // E and F (contiguous)

    knorm2<<<B_SZ, 256, 0, stream>>>(features, f8, posdot);
    kgram<<<NJOB, GT, 0, stream>>>(f8, tau_buf, index, E, F,
                                   (const float4*)s, (const float4*)u_buf,
                                   (const float4*)tau_buf, out);
    ksliver<<<NSLV, GT, 0, stream>>>(f8, tau_buf, index, E, F);
    kfin<<<B_SZ, 64, 0, stream>>>(E, F, posdot, s, tau_buf, u_buf, index, epoch, out);
}